// Round 1
// baseline (82.235 us; speedup 1.0000x reference)
//
#include <hip/hip_runtime.h>
#include <math.h>

// TropConv2D: out[b,ho,wo,f] = max_k(patch[b,ho,wo,k] + w[k,f])
//                            - min_k(patch[b,ho,wo,k] + w[k,f]) + bias[f]
// B=8, H=W=32, C=32, KH=KW=3, F=64, Ho=Wo=30, K=288.
// One 64-thread block (one wave) per (b, ho, wo-chunk of 6); lane = filter.
// Block of 64 => all spatial addressing is uniform (from blockIdx only),
// letting the compiler scalarize x loads; w loads are coalesced 256B/wave
// and reused across the 6 pixels of the chunk.

#define PIX 6  // wo positions per wave; 30 % 6 == 0

__global__ __launch_bounds__(64) void trop_kernel(
    const float* __restrict__ x,     // (8,32,32,32)
    const float* __restrict__ w,     // (288,64)
    const float* __restrict__ bias,  // (64,)
    float* __restrict__ out)         // (8,30,30,64)
{
    const int lane = threadIdx.x;        // filter index 0..63
    const int gid  = blockIdx.x;         // 0..1199
    const int chunk = gid % 5;           // which wo-chunk
    const int rowid = gid / 5;           // 0..239
    const int ho = rowid % 30;
    const int b  = rowid / 30;
    const int wo0 = chunk * PIX;

    // x[b][h][wcol][c] = x[((b*32 + h)*32 + wcol)*32 + c]
    const float* xbase = x + (((b * 32 + ho) * 32) + wo0) * 32;

    float amax[PIX], amin[PIX];
#pragma unroll
    for (int p = 0; p < PIX; ++p) {
        amax[p] = -INFINITY;
        amin[p] =  INFINITY;
    }

#pragma unroll
    for (int dydx = 0; dydx < 9; ++dydx) {
        const int dy = dydx / 3;
        const int dx = dydx % 3;
        const float* xp = xbase + (dy * 32 + dx) * 32;   // row dy, col shift dx
        const float* wp = w + dydx * 32 * 64 + lane;     // k = dydx*32 + c

        for (int c = 0; c < 32; c += 4) {
            // 4 coalesced w loads (256B per wave each), reused for all 6 pixels
            const float w0 = wp[(c + 0) * 64];
            const float w1 = wp[(c + 1) * 64];
            const float w2 = wp[(c + 2) * 64];
            const float w3 = wp[(c + 3) * 64];
#pragma unroll
            for (int p = 0; p < PIX; ++p) {
                const float4 xv = *(const float4*)(xp + p * 32 + c);  // uniform
                const float s0 = xv.x + w0;
                const float s1 = xv.y + w1;
                const float s2 = xv.z + w2;
                const float s3 = xv.w + w3;
                // chains fold to v_max3_f32 / v_min3_f32
                amax[p] = fmaxf(fmaxf(fmaxf(fmaxf(amax[p], s0), s1), s2), s3);
                amin[p] = fminf(fminf(fminf(fminf(amin[p], s0), s1), s2), s3);
            }
        }
    }

    const float bv = bias[lane];
    float* op = out + (((b * 30 + ho) * 30) + wo0) * 64 + lane;
#pragma unroll
    for (int p = 0; p < PIX; ++p)
        op[p * 64] = amax[p] - amin[p] + bv;
}

extern "C" void kernel_launch(void* const* d_in, const int* in_sizes, int n_in,
                              void* d_out, int out_size, void* d_ws, size_t ws_size,
                              hipStream_t stream) {
    const float* x    = (const float*)d_in[0];
    const float* w    = (const float*)d_in[1];
    const float* bias = (const float*)d_in[2];
    float* out = (float*)d_out;

    // 8 batches * 30 rows * (30/6) chunks = 1200 blocks of 1 wave each
    trop_kernel<<<dim3(1200), dim3(64), 0, stream>>>(x, w, bias, out);
}

// Round 2
// 77.790 us; speedup vs baseline: 1.0571x; 1.0571x over previous
//
#include <hip/hip_runtime.h>
#include <math.h>

// TropConv2D: out[b,ho,wo,f] = max_k(patch + w) - min_k(patch + w) + bias
// B=8, H=W=32, C=32, KH=KW=3, F=64, Ho=Wo=30, K=288. 7200 output pixels.
//
// R2 structure: 256-thread blocks (4 waves). Each wave owns PIX=2 pixels
// (flattened pixel ids), lane = filter. Per 3x3 tap, the 32x64-float w-slice
// (8 KiB) is staged into LDS, double-buffered: global->VGPR prefetch of
// slice t+1 issues before compute of slice t, ds_write after, one barrier
// per tap. w reads are conflict-free ds_read_b32 (lane-consecutive).
// 900 blocks => ~14 waves/CU for latency hiding (R1 had ~4.7).

#define PIX 2
#define TPB 256  // 4 waves

__global__ __launch_bounds__(TPB) void trop_kernel(
    const float* __restrict__ x,     // (8,32,32,32)
    const float* __restrict__ w,     // (288,64) = 9 taps * (32,64)
    const float* __restrict__ bias,  // (64,)
    float* __restrict__ out)         // (8,30,30,64) = (7200,64)
{
    __shared__ float wlds[2][32 * 64];  // 2 x 8 KiB tap slices

    const int tid  = threadIdx.x;
    const int lane = tid & 63;
    const int wv   = tid >> 6;

    const int pix0 = blockIdx.x * (4 * PIX) + wv * PIX;  // 0..7198

    const float* xp[PIX];
#pragma unroll
    for (int p = 0; p < PIX; ++p) {
        const int pid = pix0 + p;
        const int wo = pid % 30;
        const int t  = pid / 30;
        const int ho = t % 30;
        const int b  = t / 30;
        xp[p] = x + (((b * 32 + ho) * 32) + wo) * 32;
    }

    float amax[PIX], amin[PIX];
#pragma unroll
    for (int p = 0; p < PIX; ++p) { amax[p] = -INFINITY; amin[p] = INFINITY; }

    // Stage slice 0 (tap 0): 256 threads x 2 float4 = 8 KiB
    {
        const float4* src = (const float4*)w;
        ((float4*)wlds[0])[tid]       = src[tid];
        ((float4*)wlds[0])[tid + 256] = src[tid + 256];
    }
    __syncthreads();

#pragma unroll
    for (int tap = 0; tap < 9; ++tap) {
        const int cur = tap & 1;
        const int nxt = cur ^ 1;

        // Prefetch next tap's slice into registers (overlaps with compute).
        const int ntap = (tap < 8) ? tap + 1 : 8;  // last prefetch is a dummy re-read
        const float4* src = (const float4*)(w + ntap * 2048);
        const float4 r0 = src[tid];
        const float4 r1 = src[tid + 256];

        const int dy = tap / 3;
        const int dx = tap % 3;
        const int xoff = (dy * 32 + dx) * 32;

#pragma unroll
        for (int c = 0; c < 32; c += 4) {
            const float w0 = wlds[cur][(c + 0) * 64 + lane];
            const float w1 = wlds[cur][(c + 1) * 64 + lane];
            const float w2 = wlds[cur][(c + 2) * 64 + lane];
            const float w3 = wlds[cur][(c + 3) * 64 + lane];
#pragma unroll
            for (int p = 0; p < PIX; ++p) {
                const float4 xv = *(const float4*)(xp[p] + xoff + c);  // wave-uniform
                const float s0 = xv.x + w0;
                const float s1 = xv.y + w1;
                const float s2 = xv.z + w2;
                const float s3 = xv.w + w3;
                amax[p] = fmaxf(fmaxf(fmaxf(fmaxf(amax[p], s0), s1), s2), s3);
                amin[p] = fminf(fminf(fminf(fminf(amin[p], s0), s1), s2), s3);
            }
        }

        // Write prefetched slice into the other buffer, then sync.
        ((float4*)wlds[nxt])[tid]       = r0;
        ((float4*)wlds[nxt])[tid + 256] = r1;
        __syncthreads();
    }

    const float bv = bias[lane];
#pragma unroll
    for (int p = 0; p < PIX; ++p)
        out[(pix0 + p) * 64 + lane] = amax[p] - amin[p] + bv;
}

extern "C" void kernel_launch(void* const* d_in, const int* in_sizes, int n_in,
                              void* d_out, int out_size, void* d_ws, size_t ws_size,
                              hipStream_t stream) {
    const float* x    = (const float*)d_in[0];
    const float* w    = (const float*)d_in[1];
    const float* bias = (const float*)d_in[2];
    float* out = (float*)d_out;

    // 7200 pixels / (4 waves * 2 pixels) = 900 blocks
    trop_kernel<<<dim3(900), dim3(TPB), 0, stream>>>(x, w, bias, out);
}